// Round 13
// baseline (193.738 us; speedup 1.0000x reference)
//
#include <hip/hip_runtime.h>

#define SQ 2048
#define DH 128
#define KVB 64

typedef __bf16 bf16x8 __attribute__((ext_vector_type(8)));
typedef float f32x16 __attribute__((ext_vector_type(16)));

__device__ __forceinline__ f32x16 mfma32(bf16x8 a, bf16x8 b, f32x16 c){
  return __builtin_amdgcn_mfma_f32_32x32x16_bf16(a, b, c, 0, 0, 0);
}

#define EXP2 __builtin_amdgcn_exp2f

// f32 -> bf16 RNE
__device__ __forceinline__ unsigned short f2bf(float f){
  unsigned u = __builtin_bit_cast(unsigned, f);
  u += 0x7fffu + ((u >> 16) & 1u);
  return (unsigned short)(u >> 16);
}
__device__ __forceinline__ unsigned packbf(float a, float b){
  return (unsigned)f2bf(a) | ((unsigned)f2bf(b) << 16);
}

// emulated v_permlane32_swap
__device__ __forceinline__ void swap32(unsigned a, unsigned b, bool h, unsigned &x, unsigned &y){
  unsigned sb = __shfl_xor(b, 32);
  unsigned sa = __shfl_xor(a, 32);
  x = h ? sb : a;
  y = h ? b : sa;
}

__device__ __forceinline__ bf16x8 mkfrag(unsigned w0, unsigned w1, unsigned w2, unsigned w3){
  uint4 t; t.x = w0; t.y = w1; t.z = w2; t.w = w3;
  return __builtin_bit_cast(bf16x8, t);
}

__global__ __launch_bounds__(256, 2)
void attn_fwd(const float* __restrict__ Q,
              const float* __restrict__ K,
              const float* __restrict__ V,
              float* __restrict__ O)
{
  // LDS: K tile [64][128] bf16 (16KB, XOR-swizzled rows) + Vt tile [128][64] bf16 (16KB, XOR-swizzled)
  __shared__ __align__(16) unsigned char smem[32768];
  const int VT = 16384;

  const int tid  = threadIdx.x;
  const int lane = tid & 63;
  const int wid  = tid >> 6;
  const int col  = lane & 31;   // q (QK) / d (PV) fragment row
  const int hi   = lane >> 5;

  // LPT: largest causal tiles dispatch first
  const int qt = 15 - (blockIdx.x & 15);
  const int bh = blockIdx.x >> 4;
  const int nt = 2*qt + 2;

  const size_t base = (size_t)bh * SQ * DH;
  const float* Qg = Q + base;
  const float* Kg = K + base;
  const float* Vg = V + base;
  float* Og = O + base;

  const int Q0 = qt*128 + wid*32;   // this wave's first q row
  const int qg = Q0 + col;          // this lane's q row

  // Q fragments (B-operand: lane holds Q[q=col][d = dc*16 + hi*8 + j])
  bf16x8 qf[8];
  #pragma unroll
  for (int dc = 0; dc < 8; ++dc){
    const float* src = Qg + (size_t)qg*DH + dc*16 + hi*8;
    float4 f0 = *(const float4*)(src);
    float4 f1 = *(const float4*)(src + 4);
    uint4 tq;
    tq.x = packbf(f0.x, f0.y); tq.y = packbf(f0.z, f0.w);
    tq.z = packbf(f1.x, f1.y); tq.w = packbf(f1.z, f1.w);
    qf[dc] = __builtin_bit_cast(bf16x8, tq);
  }

  f32x16 o0 = {}, o1 = {}, o2 = {}, o3 = {};   // O^T acc: d-blocks 0..3
  float m = -1e30f, lsum = 0.f;

  const float SC = 0.08838834764831845f * 1.4426950408889634f; // 1/sqrt(128) * log2(e)

  const int i4 = lane & 3;
  const int d0 = (lane >> 2)*8;

  for (int t = 0; t < nt; ++t){
    const int kvb = t * KVB;
    __syncthreads();

    // ---- stage K tile (fp32 -> bf16): rows [kvb, kvb+64), swizzled byte ^= (row&7)<<4 ----
    #pragma unroll
    for (int i = 0; i < 4; ++i){
      int c = i*256 + tid;                // 1024 chunks of 8 bf16
      int r = c >> 4, dc = c & 15;
      const float* src = Kg + (size_t)(kvb + r)*DH + dc*8;
      float4 f0 = *(const float4*)(src);
      float4 f1 = *(const float4*)(src + 4);
      uint4 kv;
      kv.x = packbf(f0.x, f0.y); kv.y = packbf(f0.z, f0.w);
      kv.z = packbf(f1.x, f1.y); kv.w = packbf(f1.z, f1.w);
      *(uint4*)&smem[r*256 + ((dc*16) ^ ((r & 7) << 4))] = kv;
    }

    // ---- stage V transposed (fp32 -> bf16): Vt[d][k] via in-register 4x4 word transpose ----
    #pragma unroll
    for (int it = 0; it < 4; ++it){
      int r0 = wid*16 + it*4;             // 4 consecutive k-rows
      int row = r0 + i4;
      const float* src = Vg + (size_t)(kvb + row)*DH + d0;
      float4 f0 = *(const float4*)(src);
      float4 f1 = *(const float4*)(src + 4);
      unsigned M0 = packbf(f0.x, f0.y), M1 = packbf(f0.z, f0.w);
      unsigned M2 = packbf(f1.x, f1.y), M3 = packbf(f1.z, f1.w);
      // butterfly word transpose across the quad
      unsigned t0=__shfl_xor(M1,1), t1=__shfl_xor(M0,1), t2=__shfl_xor(M3,1), t3=__shfl_xor(M2,1);
      bool ob1 = i4 & 1;
      unsigned N0 = ob1 ? t0 : M0;
      unsigned N1 = ob1 ? M1 : t1;
      unsigned N2 = ob1 ? t2 : M2;
      unsigned N3 = ob1 ? M3 : t3;
      unsigned u0s=__shfl_xor(N2,2), u1s=__shfl_xor(N3,2), u2s=__shfl_xor(N0,2), u3s=__shfl_xor(N1,2);
      bool ob2 = i4 & 2;
      unsigned F0 = ob2 ? u0s : N0;   // F_c = V[kvb+r0+c][d, d+1], d = d0+2*i4
      unsigned F1 = ob2 ? u1s : N1;
      unsigned F2 = ob2 ? N2 : u2s;
      unsigned F3 = ob2 ? N3 : u3s;
      int d = d0 + 2*i4;
      unsigned lo0 = (F0 & 0xffffu) | (F1 << 16);
      unsigned lo1 = (F2 & 0xffffu) | (F3 << 16);
      unsigned hi0 = (F0 >> 16) | (F1 & 0xffff0000u);
      unsigned hi1 = (F2 >> 16) | (F3 & 0xffff0000u);
      int cb = r0*2;
      *(uint2*)&smem[VT + d*128     + (cb ^ (( d    & 7) << 4))] = make_uint2(lo0, lo1);
      *(uint2*)&smem[VT + (d+1)*128 + (cb ^ (((d+1) & 7) << 4))] = make_uint2(hi0, hi1);
    }
    __syncthreads();

    if (kvb > Q0 + 31) continue;   // this wave fully masked for this tile

    // ---- QK^T (swapped): S^T[k][q], two 32-wide k halves ----
    f32x16 s0 = {}, s1 = {};
    #pragma unroll
    for (int dc = 0; dc < 8; ++dc){
      uint4 rk = *(const uint4*)&smem[col*256 + ((dc*32 + hi*16) ^ ((col & 7) << 4))];
      s0 = mfma32(__builtin_bit_cast(bf16x8, rk), qf[dc], s0);
    }
    #pragma unroll
    for (int dc = 0; dc < 8; ++dc){
      int r = 32 + col;
      uint4 rk = *(const uint4*)&smem[r*256 + ((dc*32 + hi*16) ^ ((r & 7) << 4))];
      s1 = mfma32(__builtin_bit_cast(bf16x8, rk), qf[dc], s1);
    }

    // scale into exp2 domain + causal mask
    s0 = s0 * SC; s1 = s1 * SC;
    if (kvb + 63 > Q0){
      #pragma unroll
      for (int r = 0; r < 16; ++r){
        int kl = (r & 3) + 8*(r >> 2) + 4*hi;
        if (kvb + kl      > qg) s0[r] = -1e30f;
        if (kvb + 32 + kl > qg) s1[r] = -1e30f;
      }
    }

    // online softmax update
    float tmax = -1e30f;
    #pragma unroll
    for (int r = 0; r < 16; ++r){ tmax = fmaxf(tmax, s0[r]); tmax = fmaxf(tmax, s1[r]); }
    tmax = fmaxf(tmax, __shfl_xor(tmax, 32));
    float mnew  = fmaxf(m, tmax);
    float alpha = EXP2(m - mnew);
    m = mnew;
    lsum *= alpha;
    o0 *= alpha; o1 *= alpha; o2 *= alpha; o3 *= alpha;

    float ps = 0.f;
    #pragma unroll
    for (int r = 0; r < 16; ++r){ float e = EXP2(s0[r] - m); s0[r] = e; ps += e; }
    #pragma unroll
    for (int r = 0; r < 16; ++r){ float e = EXP2(s1[r] - m); s1[r] = e; ps += e; }
    lsum += ps;

    // ---- build P fragments (bf16) via pack + half-swap (== HK permlane32_swap recipe) ----
    unsigned ua0 = packbf(s0[0],  s0[1]),  ua1 = packbf(s0[2],  s0[3]);
    unsigned ua2 = packbf(s0[4],  s0[5]),  ua3 = packbf(s0[6],  s0[7]);
    unsigned ua4 = packbf(s0[8],  s0[9]),  ua5 = packbf(s0[10], s0[11]);
    unsigned ua6 = packbf(s0[12], s0[13]), ua7 = packbf(s0[14], s0[15]);
    unsigned ub0 = packbf(s1[0],  s1[1]),  ub1 = packbf(s1[2],  s1[3]);
    unsigned ub2 = packbf(s1[4],  s1[5]),  ub3 = packbf(s1[6],  s1[7]);
    unsigned ub4 = packbf(s1[8],  s1[9]),  ub5 = packbf(s1[10], s1[11]);
    unsigned ub6 = packbf(s1[12], s1[13]), ub7 = packbf(s1[14], s1[15]);
    bool h = (bool)hi;
    unsigned w0, w1, w2, w3;
    bf16x8 pf[4];
    swap32(ua0, ua2, h, w0, w2); swap32(ua1, ua3, h, w1, w3); pf[0] = mkfrag(w0,w1,w2,w3);
    swap32(ua4, ua6, h, w0, w2); swap32(ua5, ua7, h, w1, w3); pf[1] = mkfrag(w0,w1,w2,w3);
    swap32(ub0, ub2, h, w0, w2); swap32(ub1, ub3, h, w1, w3); pf[2] = mkfrag(w0,w1,w2,w3);
    swap32(ub4, ub6, h, w0, w2); swap32(ub5, ub7, h, w1, w3); pf[3] = mkfrag(w0,w1,w2,w3);

    // ---- PV: O^T[d][q] += V^T-frag x P-frag ----
    #pragma unroll
    for (int cc = 0; cc < 4; ++cc){
      #pragma unroll
      for (int db = 0; db < 4; ++db){
        int rowd = db*32 + col;
        uint4 rv = *(const uint4*)&smem[VT + rowd*128 + ((cc*32 + hi*16) ^ ((rowd & 7) << 4))];
        f32x16& oo = (db==0)?o0:(db==1)?o1:(db==2)?o2:o3;
        oo = mfma32(__builtin_bit_cast(bf16x8, rv), pf[cc], oo);
      }
    }
  }

  // ---- epilogue: fp32 output ----
  lsum += __shfl_xor(lsum, 32);
  float inv = 1.0f / lsum;
  #pragma unroll
  for (int db = 0; db < 4; ++db){
    const f32x16& oo = (db==0)?o0:(db==1)?o1:(db==2)?o2:o3;
    #pragma unroll
    for (int rg = 0; rg < 4; ++rg){
      float4 w;
      w.x = oo[rg*4+0]*inv; w.y = oo[rg*4+1]*inv;
      w.z = oo[rg*4+2]*inv; w.w = oo[rg*4+3]*inv;
      *(float4*)(Og + (size_t)qg*DH + db*32 + rg*8 + hi*4) = w;
    }
  }
}

extern "C" void kernel_launch(void* const* d_in, const int* in_sizes, int n_in,
                              void* d_out, int out_size, void* d_ws, size_t ws_size,
                              hipStream_t stream) {
  // R12 diagnosis: output dtype is FP32 (reference returns float32; docs: d_out
  // holds the reference's OUTPUT dtype). All prior rounds wrote packed bf16 ->
  // every perm failed at ~5. Inputs in documented dict order: q, k, v.
  const float* q = (const float*)d_in[0];
  const float* k = (const float*)d_in[1];
  const float* v = (const float*)d_in[2];
  float* out = (float*)d_out;
  dim3 grid(512), block(256);
  attn_fwd<<<grid, block, 0, stream>>>(q, k, v, out);
}

// Round 14
// 166.769 us; speedup vs baseline: 1.1617x; 1.1617x over previous
//
#include <hip/hip_runtime.h>

#define SQ 2048
#define DH 128
#define KVB 64

typedef __bf16 bf16x8 __attribute__((ext_vector_type(8)));
typedef float f32x16 __attribute__((ext_vector_type(16)));

__device__ __forceinline__ f32x16 mfma32(bf16x8 a, bf16x8 b, f32x16 c){
  return __builtin_amdgcn_mfma_f32_32x32x16_bf16(a, b, c, 0, 0, 0);
}

#define EXP2 __builtin_amdgcn_exp2f

// f32 -> bf16 RNE
__device__ __forceinline__ unsigned short f2bf(float f){
  unsigned u = __builtin_bit_cast(unsigned, f);
  u += 0x7fffu + ((u >> 16) & 1u);
  return (unsigned short)(u >> 16);
}
__device__ __forceinline__ unsigned packbf(float a, float b){
  return (unsigned)f2bf(a) | ((unsigned)f2bf(b) << 16);
}

// emulated v_permlane32_swap
__device__ __forceinline__ void swap32(unsigned a, unsigned b, bool h, unsigned &x, unsigned &y){
  unsigned sb = __shfl_xor(b, 32);
  unsigned sa = __shfl_xor(a, 32);
  x = h ? sb : a;
  y = h ? b : sa;
}

__device__ __forceinline__ bf16x8 mkfrag(unsigned w0, unsigned w1, unsigned w2, unsigned w3){
  uint4 t; t.x = w0; t.y = w1; t.z = w2; t.w = w3;
  return __builtin_bit_cast(bf16x8, t);
}

__global__ __launch_bounds__(256, 2)
void attn_fwd(const float* __restrict__ Q,
              const float* __restrict__ K,
              const float* __restrict__ V,
              float* __restrict__ O)
{
  // LDS: K tile [64][128] bf16 (16KB, XOR-swizzled rows) + Vt tile [128][64] bf16 (16KB, XOR-swizzled)
  __shared__ __align__(16) unsigned char smem[32768];
  const int VT = 16384;

  const int tid  = threadIdx.x;
  const int lane = tid & 63;
  const int wid  = tid >> 6;
  const int col  = lane & 31;   // q (QK) / d (PV) fragment row
  const int hi   = lane >> 5;

  // XCD-aware mapping (T1): block b -> xcd = b&7 (round-robin dispatch).
  // Each XCD hosts only bh with bh%8 == xcd -> K/V (2MB/bh) stays L2-resident.
  // seq<32: big causal tiles (qt=15-j); seq>=32: complementary small (qt=j).
  // Under round-robin CU assignment, CU c gets seq c and c+32: same bh,
  // qt pair (15-j, j) -> exactly 34 KV-tile units per CU (balanced).
  const int b   = blockIdx.x;
  const int xcd = b & 7;
  const int seq = b >> 3;          // 0..63
  const int hlf = seq >> 5;        // 0 = big half, 1 = small half
  const int r5  = seq & 31;
  const int bh4 = r5 >> 3;         // 0..3
  const int j   = r5 & 7;          // 0..7
  const int bh  = xcd + 8*bh4;
  const int qt  = hlf ? j : (15 - j);
  const int nt  = 2*qt + 2;

  const size_t base = (size_t)bh * SQ * DH;
  const float* Qg = Q + base;
  const float* Kg = K + base;
  const float* Vg = V + base;
  float* Og = O + base;

  const int Q0 = qt*128 + wid*32;   // this wave's first q row
  const int qg = Q0 + col;          // this lane's q row

  // Q fragments (B-operand: lane holds Q[q=col][d = dc*16 + hi*8 + j])
  bf16x8 qf[8];
  #pragma unroll
  for (int dc = 0; dc < 8; ++dc){
    const float* src = Qg + (size_t)qg*DH + dc*16 + hi*8;
    float4 f0 = *(const float4*)(src);
    float4 f1 = *(const float4*)(src + 4);
    uint4 tq;
    tq.x = packbf(f0.x, f0.y); tq.y = packbf(f0.z, f0.w);
    tq.z = packbf(f1.x, f1.y); tq.w = packbf(f1.z, f1.w);
    qf[dc] = __builtin_bit_cast(bf16x8, tq);
  }

  f32x16 o0 = {}, o1 = {}, o2 = {}, o3 = {};   // O^T acc: d-blocks 0..3
  float m = -1e30f, lsum = 0.f;

  const float SC = 0.08838834764831845f * 1.4426950408889634f; // 1/sqrt(128) * log2(e)

  const int i4 = lane & 3;
  const int d0 = (lane >> 2)*8;

  for (int t = 0; t < nt; ++t){
    const int kvb = t * KVB;
    __syncthreads();

    // ---- stage K tile (fp32 -> bf16): rows [kvb, kvb+64), swizzled byte ^= (row&7)<<4 ----
    #pragma unroll
    for (int i = 0; i < 4; ++i){
      int c = i*256 + tid;                // 1024 chunks of 8 bf16
      int r = c >> 4, dc = c & 15;
      const float* src = Kg + (size_t)(kvb + r)*DH + dc*8;
      float4 f0 = *(const float4*)(src);
      float4 f1 = *(const float4*)(src + 4);
      uint4 kv;
      kv.x = packbf(f0.x, f0.y); kv.y = packbf(f0.z, f0.w);
      kv.z = packbf(f1.x, f1.y); kv.w = packbf(f1.z, f1.w);
      *(uint4*)&smem[r*256 + ((dc*16) ^ ((r & 7) << 4))] = kv;
    }

    // ---- stage V transposed (fp32 -> bf16): Vt[d][k], swizzle ((d>>1)&7)<<4 ----
    // (d is even per-lane; d/2 = lane mod 8 within each 8-lane group ->
    //  8 distinct 16B slots -> conflict-free writes; PV reads 2-way = free)
    #pragma unroll
    for (int it = 0; it < 4; ++it){
      int r0 = wid*16 + it*4;             // 4 consecutive k-rows
      int row = r0 + i4;
      const float* src = Vg + (size_t)(kvb + row)*DH + d0;
      float4 f0 = *(const float4*)(src);
      float4 f1 = *(const float4*)(src + 4);
      unsigned M0 = packbf(f0.x, f0.y), M1 = packbf(f0.z, f0.w);
      unsigned M2 = packbf(f1.x, f1.y), M3 = packbf(f1.z, f1.w);
      // butterfly word transpose across the quad
      unsigned t0=__shfl_xor(M1,1), t1=__shfl_xor(M0,1), t2=__shfl_xor(M3,1), t3=__shfl_xor(M2,1);
      bool ob1 = i4 & 1;
      unsigned N0 = ob1 ? t0 : M0;
      unsigned N1 = ob1 ? M1 : t1;
      unsigned N2 = ob1 ? t2 : M2;
      unsigned N3 = ob1 ? M3 : t3;
      unsigned u0s=__shfl_xor(N2,2), u1s=__shfl_xor(N3,2), u2s=__shfl_xor(N0,2), u3s=__shfl_xor(N1,2);
      bool ob2 = i4 & 2;
      unsigned F0 = ob2 ? u0s : N0;   // F_c = V[kvb+r0+c][d, d+1], d = d0+2*i4
      unsigned F1 = ob2 ? u1s : N1;
      unsigned F2 = ob2 ? N2 : u2s;
      unsigned F3 = ob2 ? N3 : u3s;
      int d = d0 + 2*i4;
      unsigned lo0 = (F0 & 0xffffu) | (F1 << 16);
      unsigned lo1 = (F2 & 0xffffu) | (F3 << 16);
      unsigned hi0 = (F0 >> 16) | (F1 & 0xffff0000u);
      unsigned hi1 = (F2 >> 16) | (F3 & 0xffff0000u);
      int cb = r0*2;
      int sA = ((d >> 1) & 7) << 4;       // same slot for rows d and d+1
      *(uint2*)&smem[VT + d*128     + (cb ^ sA)] = make_uint2(lo0, lo1);
      *(uint2*)&smem[VT + (d+1)*128 + (cb ^ sA)] = make_uint2(hi0, hi1);
    }
    __syncthreads();

    if (kvb > Q0 + 31) continue;   // this wave fully masked for this tile

    // ---- QK^T (swapped): S^T[k][q], two 32-wide k halves ----
    f32x16 s0 = {}, s1 = {};
    #pragma unroll
    for (int dc = 0; dc < 8; ++dc){
      uint4 rk = *(const uint4*)&smem[col*256 + ((dc*32 + hi*16) ^ ((col & 7) << 4))];
      s0 = mfma32(__builtin_bit_cast(bf16x8, rk), qf[dc], s0);
    }
    #pragma unroll
    for (int dc = 0; dc < 8; ++dc){
      int r = 32 + col;
      uint4 rk = *(const uint4*)&smem[r*256 + ((dc*32 + hi*16) ^ ((r & 7) << 4))];
      s1 = mfma32(__builtin_bit_cast(bf16x8, rk), qf[dc], s1);
    }

    // scale into exp2 domain + causal mask
    s0 = s0 * SC; s1 = s1 * SC;
    if (kvb + 63 > Q0){
      #pragma unroll
      for (int r = 0; r < 16; ++r){
        int kl = (r & 3) + 8*(r >> 2) + 4*hi;
        if (kvb + kl      > qg) s0[r] = -1e30f;
        if (kvb + 32 + kl > qg) s1[r] = -1e30f;
      }
    }

    // online softmax update
    float tmax = -1e30f;
    #pragma unroll
    for (int r = 0; r < 16; ++r){ tmax = fmaxf(tmax, s0[r]); tmax = fmaxf(tmax, s1[r]); }
    tmax = fmaxf(tmax, __shfl_xor(tmax, 32));
    float mnew  = fmaxf(m, tmax);
    float alpha = EXP2(m - mnew);
    m = mnew;
    lsum *= alpha;
    o0 *= alpha; o1 *= alpha; o2 *= alpha; o3 *= alpha;

    float ps = 0.f;
    #pragma unroll
    for (int r = 0; r < 16; ++r){ float e = EXP2(s0[r] - m); s0[r] = e; ps += e; }
    #pragma unroll
    for (int r = 0; r < 16; ++r){ float e = EXP2(s1[r] - m); s1[r] = e; ps += e; }
    lsum += ps;

    // ---- build P fragments (bf16) via pack + half-swap (== HK permlane32_swap recipe) ----
    unsigned ua0 = packbf(s0[0],  s0[1]),  ua1 = packbf(s0[2],  s0[3]);
    unsigned ua2 = packbf(s0[4],  s0[5]),  ua3 = packbf(s0[6],  s0[7]);
    unsigned ua4 = packbf(s0[8],  s0[9]),  ua5 = packbf(s0[10], s0[11]);
    unsigned ua6 = packbf(s0[12], s0[13]), ua7 = packbf(s0[14], s0[15]);
    unsigned ub0 = packbf(s1[0],  s1[1]),  ub1 = packbf(s1[2],  s1[3]);
    unsigned ub2 = packbf(s1[4],  s1[5]),  ub3 = packbf(s1[6],  s1[7]);
    unsigned ub4 = packbf(s1[8],  s1[9]),  ub5 = packbf(s1[10], s1[11]);
    unsigned ub6 = packbf(s1[12], s1[13]), ub7 = packbf(s1[14], s1[15]);
    bool h = (bool)hi;
    unsigned w0, w1, w2, w3;
    bf16x8 pf[4];
    swap32(ua0, ua2, h, w0, w2); swap32(ua1, ua3, h, w1, w3); pf[0] = mkfrag(w0,w1,w2,w3);
    swap32(ua4, ua6, h, w0, w2); swap32(ua5, ua7, h, w1, w3); pf[1] = mkfrag(w0,w1,w2,w3);
    swap32(ub0, ub2, h, w0, w2); swap32(ub1, ub3, h, w1, w3); pf[2] = mkfrag(w0,w1,w2,w3);
    swap32(ub4, ub6, h, w0, w2); swap32(ub5, ub7, h, w1, w3); pf[3] = mkfrag(w0,w1,w2,w3);

    // ---- PV: O^T[d][q] += V^T-frag x P-frag ----
    #pragma unroll
    for (int cc = 0; cc < 4; ++cc){
      #pragma unroll
      for (int db = 0; db < 4; ++db){
        int rowd = db*32 + col;
        uint4 rv = *(const uint4*)&smem[VT + rowd*128 + ((cc*32 + hi*16) ^ (((rowd >> 1) & 7) << 4))];
        f32x16& oo = (db==0)?o0:(db==1)?o1:(db==2)?o2:o3;
        oo = mfma32(__builtin_bit_cast(bf16x8, rv), pf[cc], oo);
      }
    }
  }

  // ---- epilogue: fp32 output ----
  lsum += __shfl_xor(lsum, 32);
  float inv = 1.0f / lsum;
  #pragma unroll
  for (int db = 0; db < 4; ++db){
    const f32x16& oo = (db==0)?o0:(db==1)?o1:(db==2)?o2:o3;
    #pragma unroll
    for (int rg = 0; rg < 4; ++rg){
      float4 w;
      w.x = oo[rg*4+0]*inv; w.y = oo[rg*4+1]*inv;
      w.z = oo[rg*4+2]*inv; w.w = oo[rg*4+3]*inv;
      *(float4*)(Og + (size_t)qg*DH + db*32 + rg*8 + hi*4) = w;
    }
  }
}

extern "C" void kernel_launch(void* const* d_in, const int* in_sizes, int n_in,
                              void* d_out, int out_size, void* d_ws, size_t ws_size,
                              hipStream_t stream) {
  const float* q = (const float*)d_in[0];
  const float* k = (const float*)d_in[1];
  const float* v = (const float*)d_in[2];
  float* out = (float*)d_out;
  dim3 grid(512), block(256);
  attn_fwd<<<grid, block, 0, stream>>>(q, k, v, out);
}

// Round 15
// 155.674 us; speedup vs baseline: 1.2445x; 1.0713x over previous
//
#include <hip/hip_runtime.h>

#define SQ 2048
#define DH 128
#define KVB 64

typedef __bf16 bf16x8 __attribute__((ext_vector_type(8)));
typedef float f32x16 __attribute__((ext_vector_type(16)));

__device__ __forceinline__ f32x16 mfma32(bf16x8 a, bf16x8 b, f32x16 c){
  return __builtin_amdgcn_mfma_f32_32x32x16_bf16(a, b, c, 0, 0, 0);
}

#define EXP2 __builtin_amdgcn_exp2f

// f32 -> bf16 RNE
__device__ __forceinline__ unsigned short f2bf(float f){
  unsigned u = __builtin_bit_cast(unsigned, f);
  u += 0x7fffu + ((u >> 16) & 1u);
  return (unsigned short)(u >> 16);
}
__device__ __forceinline__ unsigned packbf(float a, float b){
  return (unsigned)f2bf(a) | ((unsigned)f2bf(b) << 16);
}

// emulated v_permlane32_swap
__device__ __forceinline__ void swap32(unsigned a, unsigned b, bool h, unsigned &x, unsigned &y){
  unsigned sb = __shfl_xor(b, 32);
  unsigned sa = __shfl_xor(a, 32);
  x = h ? sb : a;
  y = h ? b : sa;
}

__device__ __forceinline__ bf16x8 mkfrag(unsigned w0, unsigned w1, unsigned w2, unsigned w3){
  uint4 t; t.x = w0; t.y = w1; t.z = w2; t.w = w3;
  return __builtin_bit_cast(bf16x8, t);
}

__global__ __launch_bounds__(256, 2)
void attn_fwd(const float* __restrict__ Q,
              const float* __restrict__ K,
              const float* __restrict__ V,
              float* __restrict__ O)
{
  // Double-buffered LDS: 2 x { K[64][128]bf16 swz | Vt[128][64]bf16 swz } = 64KB
  __shared__ __align__(16) unsigned char smem[65536];

  const int tid  = threadIdx.x;
  const int lane = tid & 63;
  const int wid  = tid >> 6;
  const int col  = lane & 31;
  const int hi   = lane >> 5;

  // XCD-aware mapping (T1) + LPT pairing (R14)
  const int b   = blockIdx.x;
  const int xcd = b & 7;
  const int seq = b >> 3;
  const int hlf = seq >> 5;
  const int r5  = seq & 31;
  const int bh4 = r5 >> 3;
  const int j   = r5 & 7;
  const int bh  = xcd + 8*bh4;
  const int qt  = hlf ? j : (15 - j);
  const int nt  = 2*qt + 2;

  const size_t base = (size_t)bh * SQ * DH;
  const float* Qg = Q + base;
  const float* Kg = K + base;
  const float* Vg = V + base;
  float* Og = O + base;

  const int Q0 = qt*128 + wid*32;
  const int qg = Q0 + col;

  const int i4 = lane & 3;
  const int d0 = (lane >> 2)*8;

  // Q fragments
  bf16x8 qf[8];
  #pragma unroll
  for (int dc = 0; dc < 8; ++dc){
    const float* src = Qg + (size_t)qg*DH + dc*16 + hi*8;
    float4 f0 = *(const float4*)(src);
    float4 f1 = *(const float4*)(src + 4);
    uint4 tq;
    tq.x = packbf(f0.x, f0.y); tq.y = packbf(f0.z, f0.w);
    tq.z = packbf(f1.x, f1.y); tq.w = packbf(f1.z, f1.w);
    qf[dc] = __builtin_bit_cast(bf16x8, tq);
  }

  f32x16 o0 = {}, o1 = {}, o2 = {}, o3 = {};
  float m = -1e30f, lsum = 0.f;
  const float SC = 0.08838834764831845f * 1.4426950408889634f;

  // staging registers (in flight across compute)
  float4 kr[8], vr[8];

  // ---- load tile kvb into registers (issue-early half of T14 split) ----
  auto LOADT = [&](int kvb){
    #pragma unroll
    for (int i = 0; i < 4; ++i){
      int c = i*256 + tid, r = c >> 4, dc = c & 15;
      const float* src = Kg + (size_t)(kvb + r)*DH + dc*8;
      kr[2*i]   = *(const float4*)(src);
      kr[2*i+1] = *(const float4*)(src + 4);
    }
    #pragma unroll
    for (int it = 0; it < 4; ++it){
      int row = wid*16 + it*4 + i4;
      const float* src = Vg + (size_t)(kvb + row)*DH + d0;
      vr[2*it]   = *(const float4*)(src);
      vr[2*it+1] = *(const float4*)(src + 4);
    }
  };

  // ---- pack + transpose + LDS write (write-late half) ----
  auto STORET = [&](int bsel){
    const int bb = bsel * 32768;
    #pragma unroll
    for (int i = 0; i < 4; ++i){
      int c = i*256 + tid, r = c >> 4, dc = c & 15;
      uint4 kv;
      kv.x = packbf(kr[2*i].x,   kr[2*i].y);
      kv.y = packbf(kr[2*i].z,   kr[2*i].w);
      kv.z = packbf(kr[2*i+1].x, kr[2*i+1].y);
      kv.w = packbf(kr[2*i+1].z, kr[2*i+1].w);
      *(uint4*)&smem[bb + r*256 + ((dc*16) ^ ((r & 7) << 4))] = kv;
    }
    #pragma unroll
    for (int it = 0; it < 4; ++it){
      int r0 = wid*16 + it*4;
      unsigned M0 = packbf(vr[2*it].x,   vr[2*it].y);
      unsigned M1 = packbf(vr[2*it].z,   vr[2*it].w);
      unsigned M2 = packbf(vr[2*it+1].x, vr[2*it+1].y);
      unsigned M3 = packbf(vr[2*it+1].z, vr[2*it+1].w);
      unsigned t0=__shfl_xor(M1,1), t1=__shfl_xor(M0,1), t2=__shfl_xor(M3,1), t3=__shfl_xor(M2,1);
      bool ob1 = i4 & 1;
      unsigned N0 = ob1 ? t0 : M0;
      unsigned N1 = ob1 ? M1 : t1;
      unsigned N2 = ob1 ? t2 : M2;
      unsigned N3 = ob1 ? M3 : t3;
      unsigned u0s=__shfl_xor(N2,2), u1s=__shfl_xor(N3,2), u2s=__shfl_xor(N0,2), u3s=__shfl_xor(N1,2);
      bool ob2 = i4 & 2;
      unsigned F0 = ob2 ? u0s : N0;
      unsigned F1 = ob2 ? u1s : N1;
      unsigned F2 = ob2 ? N2 : u2s;
      unsigned F3 = ob2 ? N3 : u3s;
      int d = d0 + 2*i4;
      unsigned lo0 = (F0 & 0xffffu) | (F1 << 16);
      unsigned lo1 = (F2 & 0xffffu) | (F3 << 16);
      unsigned hi0 = (F0 >> 16) | (F1 & 0xffff0000u);
      unsigned hi1 = (F2 >> 16) | (F3 & 0xffff0000u);
      int cb = r0*2;
      int sA = ((d >> 1) & 7) << 4;
      *(uint2*)&smem[bb + 16384 + d*128     + (cb ^ sA)] = make_uint2(lo0, lo1);
      *(uint2*)&smem[bb + 16384 + (d+1)*128 + (cb ^ sA)] = make_uint2(hi0, hi1);
    }
  };

  // prologue: stage tile 0
  LOADT(0);
  STORET(0);
  __syncthreads();

  for (int t = 0; t < nt; ++t){
    const int kvb = t * KVB;
    const int bufc = t & 1;
    const int bb = bufc * 32768;

    if (t + 1 < nt) LOADT(kvb + KVB);   // issue next-tile loads; latency hides under compute

    if (kvb <= Q0 + 31){
      // ---- QK^T (swapped): S^T[k][q] ----
      f32x16 s0 = {}, s1 = {};
      #pragma unroll
      for (int dc = 0; dc < 8; ++dc){
        uint4 rk = *(const uint4*)&smem[bb + col*256 + ((dc*32 + hi*16) ^ ((col & 7) << 4))];
        s0 = mfma32(__builtin_bit_cast(bf16x8, rk), qf[dc], s0);
      }
      #pragma unroll
      for (int dc = 0; dc < 8; ++dc){
        int r = 32 + col;
        uint4 rk = *(const uint4*)&smem[bb + r*256 + ((dc*32 + hi*16) ^ ((r & 7) << 4))];
        s1 = mfma32(__builtin_bit_cast(bf16x8, rk), qf[dc], s1);
      }

      s0 = s0 * SC; s1 = s1 * SC;
      if (kvb + 63 > Q0){
        #pragma unroll
        for (int r = 0; r < 16; ++r){
          int kl = (r & 3) + 8*(r >> 2) + 4*hi;
          if (kvb + kl      > qg) s0[r] = -1e30f;
          if (kvb + 32 + kl > qg) s1[r] = -1e30f;
        }
      }

      float tmax = -1e30f;
      #pragma unroll
      for (int r = 0; r < 16; ++r){ tmax = fmaxf(tmax, s0[r]); tmax = fmaxf(tmax, s1[r]); }
      tmax = fmaxf(tmax, __shfl_xor(tmax, 32));
      float mnew  = fmaxf(m, tmax);
      float alpha = EXP2(m - mnew);
      m = mnew;
      lsum *= alpha;
      o0 *= alpha; o1 *= alpha; o2 *= alpha; o3 *= alpha;

      float ps = 0.f;
      #pragma unroll
      for (int r = 0; r < 16; ++r){ float e = EXP2(s0[r] - m); s0[r] = e; ps += e; }
      #pragma unroll
      for (int r = 0; r < 16; ++r){ float e = EXP2(s1[r] - m); s1[r] = e; ps += e; }
      lsum += ps;

      unsigned ua0 = packbf(s0[0],  s0[1]),  ua1 = packbf(s0[2],  s0[3]);
      unsigned ua2 = packbf(s0[4],  s0[5]),  ua3 = packbf(s0[6],  s0[7]);
      unsigned ua4 = packbf(s0[8],  s0[9]),  ua5 = packbf(s0[10], s0[11]);
      unsigned ua6 = packbf(s0[12], s0[13]), ua7 = packbf(s0[14], s0[15]);
      unsigned ub0 = packbf(s1[0],  s1[1]),  ub1 = packbf(s1[2],  s1[3]);
      unsigned ub2 = packbf(s1[4],  s1[5]),  ub3 = packbf(s1[6],  s1[7]);
      unsigned ub4 = packbf(s1[8],  s1[9]),  ub5 = packbf(s1[10], s1[11]);
      unsigned ub6 = packbf(s1[12], s1[13]), ub7 = packbf(s1[14], s1[15]);
      bool h = (bool)hi;
      unsigned w0, w1, w2, w3;
      bf16x8 pf[4];
      swap32(ua0, ua2, h, w0, w2); swap32(ua1, ua3, h, w1, w3); pf[0] = mkfrag(w0,w1,w2,w3);
      swap32(ua4, ua6, h, w0, w2); swap32(ua5, ua7, h, w1, w3); pf[1] = mkfrag(w0,w1,w2,w3);
      swap32(ub0, ub2, h, w0, w2); swap32(ub1, ub3, h, w1, w3); pf[2] = mkfrag(w0,w1,w2,w3);
      swap32(ub4, ub6, h, w0, w2); swap32(ub5, ub7, h, w1, w3); pf[3] = mkfrag(w0,w1,w2,w3);

      #pragma unroll
      for (int cc = 0; cc < 4; ++cc){
        #pragma unroll
        for (int db = 0; db < 4; ++db){
          int rowd = db*32 + col;
          uint4 rv = *(const uint4*)&smem[bb + 16384 + rowd*128 + ((cc*32 + hi*16) ^ (((rowd >> 1) & 7) << 4))];
          f32x16& oo = (db==0)?o0:(db==1)?o1:(db==2)?o2:o3;
          oo = mfma32(__builtin_bit_cast(bf16x8, rv), pf[cc], oo);
        }
      }
    }

    if (t + 1 < nt) STORET(bufc ^ 1);   // vmcnt drain lands here, after compute
    __syncthreads();                     // publishes buf t+1; frees buf t for overwrite
  }

  // ---- epilogue: fp32 output ----
  lsum += __shfl_xor(lsum, 32);
  float inv = 1.0f / lsum;
  #pragma unroll
  for (int db = 0; db < 4; ++db){
    const f32x16& oo = (db==0)?o0:(db==1)?o1:(db==2)?o2:o3;
    #pragma unroll
    for (int rg = 0; rg < 4; ++rg){
      float4 w;
      w.x = oo[rg*4+0]*inv; w.y = oo[rg*4+1]*inv;
      w.z = oo[rg*4+2]*inv; w.w = oo[rg*4+3]*inv;
      *(float4*)(Og + (size_t)qg*DH + db*32 + rg*8 + hi*4) = w;
    }
  }
}

extern "C" void kernel_launch(void* const* d_in, const int* in_sizes, int n_in,
                              void* d_out, int out_size, void* d_ws, size_t ws_size,
                              hipStream_t stream) {
  const float* q = (const float*)d_in[0];
  const float* k = (const float*)d_in[1];
  const float* v = (const float*)d_in[2];
  float* out = (float*)d_out;
  dim3 grid(512), block(256);
  attn_fwd<<<grid, block, 0, stream>>>(q, k, v, out);
}

// Round 16
// 132.353 us; speedup vs baseline: 1.4638x; 1.1762x over previous
//
#include <hip/hip_runtime.h>

#define SQ 2048
#define DH 128
#define KVB 64

typedef __bf16 bf16x8 __attribute__((ext_vector_type(8)));
typedef float f32x16 __attribute__((ext_vector_type(16)));

__device__ __forceinline__ f32x16 mfma32(bf16x8 a, bf16x8 b, f32x16 c){
  return __builtin_amdgcn_mfma_f32_32x32x16_bf16(a, b, c, 0, 0, 0);
}

#define EXP2 __builtin_amdgcn_exp2f

__device__ __forceinline__ unsigned short f2bf(float f){
  unsigned u = __builtin_bit_cast(unsigned, f);
  u += 0x7fffu + ((u >> 16) & 1u);
  return (unsigned short)(u >> 16);
}
__device__ __forceinline__ unsigned packbf(float a, float b){
  return (unsigned)f2bf(a) | ((unsigned)f2bf(b) << 16);
}

__device__ __forceinline__ void swap32(unsigned a, unsigned b, bool h, unsigned &x, unsigned &y){
  unsigned sb = __shfl_xor(b, 32);
  unsigned sa = __shfl_xor(a, 32);
  x = h ? sb : a;
  y = h ? b : sa;
}

__device__ __forceinline__ bf16x8 mkfrag(unsigned w0, unsigned w1, unsigned w2, unsigned w3){
  uint4 t; t.x = w0; t.y = w1; t.z = w2; t.w = w3;
  return __builtin_bit_cast(bf16x8, t);
}

__global__ __launch_bounds__(512, 2)
void attn_fwd(const float* __restrict__ Q,
              const float* __restrict__ K,
              const float* __restrict__ V,
              float* __restrict__ O)
{
  // dbuf LDS: 2 x { K[64][128]bf16 swz | Vt[128][64]bf16 swz } = 64KB; reused for epilogue merge
  __shared__ __align__(16) unsigned char smem[65536];
  float* SF = (float*)smem;

  const int tid  = threadIdx.x;
  const int lane = tid & 63;
  const int wid  = tid >> 6;      // 0..7
  const int rg   = wid & 3;       // row-group within q-tile
  const int par  = wid >> 2;      // KV-tile parity this wave computes
  const int col  = lane & 31;
  const int hi   = lane >> 5;
  const int i4   = lane & 3;
  const int d0   = (lane >> 2)*8;

  // 256 blocks: xcd = b&7 hosts bh%8==xcd (L2 locality); seq -> (bh4, j)
  const int b   = blockIdx.x;
  const int xcd = b & 7;
  const int seq = b >> 3;         // 0..31
  const int bh4 = seq & 3;
  const int j   = seq >> 2;       // 0..7
  const int bh  = xcd + 8*bh4;

  const size_t base = (size_t)bh * SQ * DH;
  const float* Qg = Q + base;
  const float* Kg = K + base;
  const float* Vg = V + base;
  float* Og = O + base;

  const float SC = 0.08838834764831845f * 1.4426950408889634f; // 1/sqrt(128)*log2e

  float4 kr[4], vr[4];  // staging regs (per-wave share: 2 K-chunks + 2 V-groups)

  auto LOADT = [&](int kvb){
    #pragma unroll
    for (int i = 0; i < 2; ++i){
      int c = i*512 + tid, r = c >> 4, dc = c & 15;
      const float* src = Kg + (size_t)(kvb + r)*DH + dc*8;
      kr[2*i]   = *(const float4*)(src);
      kr[2*i+1] = *(const float4*)(src + 4);
    }
    #pragma unroll
    for (int it = 0; it < 2; ++it){
      int row = wid*8 + it*4 + i4;
      const float* src = Vg + (size_t)(kvb + row)*DH + d0;
      vr[2*it]   = *(const float4*)(src);
      vr[2*it+1] = *(const float4*)(src + 4);
    }
  };

  auto STORET = [&](int bsel){
    const int bb = bsel * 32768;
    #pragma unroll
    for (int i = 0; i < 2; ++i){
      int c = i*512 + tid, r = c >> 4, dc = c & 15;
      uint4 kv;
      kv.x = packbf(kr[2*i].x,   kr[2*i].y);
      kv.y = packbf(kr[2*i].z,   kr[2*i].w);
      kv.z = packbf(kr[2*i+1].x, kr[2*i+1].y);
      kv.w = packbf(kr[2*i+1].z, kr[2*i+1].w);
      *(uint4*)&smem[bb + r*256 + ((dc*16) ^ ((r & 7) << 4))] = kv;
    }
    #pragma unroll
    for (int it = 0; it < 2; ++it){
      int r0 = wid*8 + it*4;
      unsigned M0 = packbf(vr[2*it].x,   vr[2*it].y);
      unsigned M1 = packbf(vr[2*it].z,   vr[2*it].w);
      unsigned M2 = packbf(vr[2*it+1].x, vr[2*it+1].y);
      unsigned M3 = packbf(vr[2*it+1].z, vr[2*it+1].w);
      unsigned t0=__shfl_xor(M1,1), t1=__shfl_xor(M0,1), t2=__shfl_xor(M3,1), t3=__shfl_xor(M2,1);
      bool ob1 = i4 & 1;
      unsigned N0 = ob1 ? t0 : M0;
      unsigned N1 = ob1 ? M1 : t1;
      unsigned N2 = ob1 ? t2 : M2;
      unsigned N3 = ob1 ? M3 : t3;
      unsigned u0s=__shfl_xor(N2,2), u1s=__shfl_xor(N3,2), u2s=__shfl_xor(N0,2), u3s=__shfl_xor(N1,2);
      bool ob2 = i4 & 2;
      unsigned F0 = ob2 ? u0s : N0;
      unsigned F1 = ob2 ? u1s : N1;
      unsigned F2 = ob2 ? N2 : u2s;
      unsigned F3 = ob2 ? N3 : u3s;
      int d = d0 + 2*i4;
      unsigned lo0 = (F0 & 0xffffu) | (F1 << 16);
      unsigned lo1 = (F2 & 0xffffu) | (F3 << 16);
      unsigned hi0 = (F0 >> 16) | (F1 & 0xffff0000u);
      unsigned hi1 = (F2 >> 16) | (F3 & 0xffff0000u);
      int cb = r0*2;
      int sA = ((d >> 1) & 7) << 4;
      *(uint2*)&smem[bb + 16384 + d*128     + (cb ^ sA)] = make_uint2(lo0, lo1);
      *(uint2*)&smem[bb + 16384 + (d+1)*128 + (cb ^ sA)] = make_uint2(hi0, hi1);
    }
  };

  // ---- two phases: qt = 15-j (big), then qt = j (small); every block = 34 tile-steps ----
  #pragma unroll 1
  for (int ph = 0; ph < 2; ++ph){
    const int qt = ph ? j : (15 - j);
    const int nt = 2*qt + 2;
    const int Q0 = qt*128 + rg*32;
    const int qg = Q0 + col;

    // Q fragments
    bf16x8 qf[8];
    #pragma unroll
    for (int dc = 0; dc < 8; ++dc){
      const float* src = Qg + (size_t)qg*DH + dc*16 + hi*8;
      float4 f0 = *(const float4*)(src);
      float4 f1 = *(const float4*)(src + 4);
      uint4 tq;
      tq.x = packbf(f0.x, f0.y); tq.y = packbf(f0.z, f0.w);
      tq.z = packbf(f1.x, f1.y); tq.w = packbf(f1.z, f1.w);
      qf[dc] = __builtin_bit_cast(bf16x8, tq);
    }

    f32x16 o0 = {}, o1 = {}, o2 = {}, o3 = {};
    float m = -1e30f, lsum = 0.f;

    LOADT(0);
    STORET(0);
    __syncthreads();

    #pragma unroll 1
    for (int t = 0; t < nt; ++t){
      const int kvb = t * KVB;
      const int bb = (t & 1) * 32768;

      if (t + 1 < nt) LOADT(kvb + KVB);

      if (((t ^ par) & 1) == 0 && kvb <= Q0 + 31){
        f32x16 s0 = {}, s1 = {};
        #pragma unroll
        for (int dc = 0; dc < 8; ++dc){
          uint4 rk = *(const uint4*)&smem[bb + col*256 + ((dc*32 + hi*16) ^ ((col & 7) << 4))];
          s0 = mfma32(__builtin_bit_cast(bf16x8, rk), qf[dc], s0);
        }
        #pragma unroll
        for (int dc = 0; dc < 8; ++dc){
          int r = 32 + col;
          uint4 rk = *(const uint4*)&smem[bb + r*256 + ((dc*32 + hi*16) ^ ((r & 7) << 4))];
          s1 = mfma32(__builtin_bit_cast(bf16x8, rk), qf[dc], s1);
        }

        s0 = s0 * SC; s1 = s1 * SC;
        if (kvb + 63 > Q0){
          #pragma unroll
          for (int r = 0; r < 16; ++r){
            int kl = (r & 3) + 8*(r >> 2) + 4*hi;
            if (kvb + kl      > qg) s0[r] = -1e30f;
            if (kvb + 32 + kl > qg) s1[r] = -1e30f;
          }
        }

        float tmax = -1e30f;
        #pragma unroll
        for (int r = 0; r < 16; ++r){ tmax = fmaxf(tmax, s0[r]); tmax = fmaxf(tmax, s1[r]); }
        tmax = fmaxf(tmax, __shfl_xor(tmax, 32));
        if (!__all(tmax <= m + 8.0f)){      // T13 defer-max
          float mnew  = fmaxf(m, tmax);
          float alpha = EXP2(m - mnew);
          m = mnew;
          lsum *= alpha;
          o0 *= alpha; o1 *= alpha; o2 *= alpha; o3 *= alpha;
        }

        float ps = 0.f;
        #pragma unroll
        for (int r = 0; r < 16; ++r){ float e = EXP2(s0[r] - m); s0[r] = e; ps += e; }
        #pragma unroll
        for (int r = 0; r < 16; ++r){ float e = EXP2(s1[r] - m); s1[r] = e; ps += e; }
        lsum += ps;

        unsigned ua0 = packbf(s0[0],  s0[1]),  ua1 = packbf(s0[2],  s0[3]);
        unsigned ua2 = packbf(s0[4],  s0[5]),  ua3 = packbf(s0[6],  s0[7]);
        unsigned ua4 = packbf(s0[8],  s0[9]),  ua5 = packbf(s0[10], s0[11]);
        unsigned ua6 = packbf(s0[12], s0[13]), ua7 = packbf(s0[14], s0[15]);
        unsigned ub0 = packbf(s1[0],  s1[1]),  ub1 = packbf(s1[2],  s1[3]);
        unsigned ub2 = packbf(s1[4],  s1[5]),  ub3 = packbf(s1[6],  s1[7]);
        unsigned ub4 = packbf(s1[8],  s1[9]),  ub5 = packbf(s1[10], s1[11]);
        unsigned ub6 = packbf(s1[12], s1[13]), ub7 = packbf(s1[14], s1[15]);
        bool h = (bool)hi;
        unsigned w0, w1, w2, w3;
        bf16x8 pf[4];
        swap32(ua0, ua2, h, w0, w2); swap32(ua1, ua3, h, w1, w3); pf[0] = mkfrag(w0,w1,w2,w3);
        swap32(ua4, ua6, h, w0, w2); swap32(ua5, ua7, h, w1, w3); pf[1] = mkfrag(w0,w1,w2,w3);
        swap32(ub0, ub2, h, w0, w2); swap32(ub1, ub3, h, w1, w3); pf[2] = mkfrag(w0,w1,w2,w3);
        swap32(ub4, ub6, h, w0, w2); swap32(ub5, ub7, h, w1, w3); pf[3] = mkfrag(w0,w1,w2,w3);

        #pragma unroll
        for (int cc = 0; cc < 4; ++cc){
          #pragma unroll
          for (int db = 0; db < 4; ++db){
            int rowd = db*32 + col;
            uint4 rv = *(const uint4*)&smem[bb + 16384 + rowd*128 + ((cc*32 + hi*16) ^ (((rowd >> 1) & 7) << 4))];
            f32x16& oo = (db==0)?o0:(db==1)?o1:(db==2)?o2:o3;
            oo = mfma32(__builtin_bit_cast(bf16x8, rv), pf[cc], oo);
          }
        }
      }

      if (t + 1 < nt) STORET((t + 1) & 1);
      __syncthreads();
    }

    // ---- epilogue: combine hi-halves, then parity merge via LDS (2 rounds) ----
    lsum += __shfl_xor(lsum, 32);

    float a0 = 1.f, a1 = 0.f, inv = 0.f;
    #pragma unroll 1
    for (int round = 0; round < 2; ++round){
      const f32x16& pa = round ? o2 : o0;
      const f32x16& pb = round ? o3 : o1;
      if (par == 1){
        #pragma unroll
        for (int i = 0; i < 16; ++i){
          SF[rg*2048 + i*64 + lane]      = pa[i];
          SF[rg*2048 + (16+i)*64 + lane] = pb[i];
        }
        if (round == 0){
          SF[8192 + rg*64 + lane] = m;
          SF[8448 + rg*64 + lane] = lsum;
        }
      }
      __syncthreads();
      if (par == 0){
        if (round == 0){
          float m1 = SF[8192 + rg*64 + lane];
          float l1 = SF[8448 + rg*64 + lane];
          float ms = fmaxf(m, m1);
          a0 = EXP2(m - ms);
          a1 = EXP2(m1 - ms);
          float ls = lsum*a0 + l1*a1;
          inv = 1.0f / ls;
        }
        #pragma unroll
        for (int dbi = 0; dbi < 2; ++dbi){
          const f32x16& oo = round ? (dbi ? o3 : o2) : (dbi ? o1 : o0);
          const int db = round*2 + dbi;
          #pragma unroll
          for (int rg2 = 0; rg2 < 4; ++rg2){
            float4 w;
            w.x = (oo[rg2*4+0]*a0 + SF[rg*2048 + (dbi*16 + rg2*4+0)*64 + lane]*a1) * inv;
            w.y = (oo[rg2*4+1]*a0 + SF[rg*2048 + (dbi*16 + rg2*4+1)*64 + lane]*a1) * inv;
            w.z = (oo[rg2*4+2]*a0 + SF[rg*2048 + (dbi*16 + rg2*4+2)*64 + lane]*a1) * inv;
            w.w = (oo[rg2*4+3]*a0 + SF[rg*2048 + (dbi*16 + rg2*4+3)*64 + lane]*a1) * inv;
            *(float4*)(Og + (size_t)qg*DH + db*32 + rg2*8 + hi*4) = w;
          }
        }
      }
      __syncthreads();
    }
  }
}

extern "C" void kernel_launch(void* const* d_in, const int* in_sizes, int n_in,
                              void* d_out, int out_size, void* d_ws, size_t ws_size,
                              hipStream_t stream) {
  const float* q = (const float*)d_in[0];
  const float* k = (const float*)d_in[1];
  const float* v = (const float*)d_in[2];
  float* out = (float*)d_out;
  dim3 grid(256), block(512);
  attn_fwd<<<grid, block, 0, stream>>>(q, k, v, out);
}

// Round 17
// 117.919 us; speedup vs baseline: 1.6430x; 1.1224x over previous
//
#include <hip/hip_runtime.h>

#define SQ 2048
#define DH 128
#define KVB 64

typedef __bf16 bf16x8 __attribute__((ext_vector_type(8)));
typedef float f32x16 __attribute__((ext_vector_type(16)));

__device__ __forceinline__ f32x16 mfma32(bf16x8 a, bf16x8 b, f32x16 c){
  return __builtin_amdgcn_mfma_f32_32x32x16_bf16(a, b, c, 0, 0, 0);
}

#define EXP2 __builtin_amdgcn_exp2f

__device__ __forceinline__ unsigned short f2bf(float f){
  unsigned u = __builtin_bit_cast(unsigned, f);
  u += 0x7fffu + ((u >> 16) & 1u);
  return (unsigned short)(u >> 16);
}
__device__ __forceinline__ unsigned packbf(float a, float b){
  return (unsigned)f2bf(a) | ((unsigned)f2bf(b) << 16);
}

__device__ __forceinline__ void swap32(unsigned a, unsigned b, bool h, unsigned &x, unsigned &y){
  unsigned sb = __shfl_xor(b, 32);
  unsigned sa = __shfl_xor(a, 32);
  x = h ? sb : a;
  y = h ? b : sa;
}

__device__ __forceinline__ bf16x8 mkfrag(unsigned w0, unsigned w1, unsigned w2, unsigned w3){
  uint4 t; t.x = w0; t.y = w1; t.z = w2; t.w = w3;
  return __builtin_bit_cast(bf16x8, t);
}

__global__ __launch_bounds__(512, 2)
void attn_fwd(const float* __restrict__ Q,
              const float* __restrict__ K,
              const float* __restrict__ V,
              float* __restrict__ O)
{
  // dbuf LDS: 2 x { K[64][128]bf16 swz | Vt[128][64]bf16 swz } = 64KB; reused for epilogue merge
  __shared__ __align__(16) unsigned char smem[65536];
  float* SF = (float*)smem;

  const int tid  = threadIdx.x;
  const int lane = tid & 63;
  const int wid  = tid >> 6;      // 0..7
  const int rg   = wid & 3;       // row-group within q-tile (SIMD id)
  const int par  = wid >> 2;      // k-half of each KV tile this wave computes
  const int col  = lane & 31;
  const int hi   = lane >> 5;
  const int i4   = lane & 3;
  const int d0   = (lane >> 2)*8;

  // 256 blocks: xcd = b&7 hosts bh%8==xcd (L2 locality); seq -> (bh4, j)
  const int b   = blockIdx.x;
  const int xcd = b & 7;
  const int seq = b >> 3;         // 0..31
  const int bh4 = seq & 3;
  const int j   = seq >> 2;       // 0..7
  const int bh  = xcd + 8*bh4;

  const size_t base = (size_t)bh * SQ * DH;
  const float* Qg = Q + base;
  const float* Kg = K + base;
  const float* Vg = V + base;
  float* Og = O + base;

  const float SC = 0.08838834764831845f * 1.4426950408889634f; // 1/sqrt(128)*log2e

  float4 kr[4], vr[4];  // staging regs (8-way split across waves)

  auto LOADT = [&](int kvb){
    #pragma unroll
    for (int i = 0; i < 2; ++i){
      int c = i*512 + tid, r = c >> 4, dc = c & 15;
      const float* src = Kg + (size_t)(kvb + r)*DH + dc*8;
      kr[2*i]   = *(const float4*)(src);
      kr[2*i+1] = *(const float4*)(src + 4);
    }
    #pragma unroll
    for (int it = 0; it < 2; ++it){
      int row = wid*8 + it*4 + i4;
      const float* src = Vg + (size_t)(kvb + row)*DH + d0;
      vr[2*it]   = *(const float4*)(src);
      vr[2*it+1] = *(const float4*)(src + 4);
    }
  };

  auto STORET = [&](int bsel){
    const int bb = bsel * 32768;
    #pragma unroll
    for (int i = 0; i < 2; ++i){
      int c = i*512 + tid, r = c >> 4, dc = c & 15;
      uint4 kv;
      kv.x = packbf(kr[2*i].x,   kr[2*i].y);
      kv.y = packbf(kr[2*i].z,   kr[2*i].w);
      kv.z = packbf(kr[2*i+1].x, kr[2*i+1].y);
      kv.w = packbf(kr[2*i+1].z, kr[2*i+1].w);
      *(uint4*)&smem[bb + r*256 + ((dc*16) ^ ((r & 7) << 4))] = kv;
    }
    #pragma unroll
    for (int it = 0; it < 2; ++it){
      int r0 = wid*8 + it*4;
      unsigned M0 = packbf(vr[2*it].x,   vr[2*it].y);
      unsigned M1 = packbf(vr[2*it].z,   vr[2*it].w);
      unsigned M2 = packbf(vr[2*it+1].x, vr[2*it+1].y);
      unsigned M3 = packbf(vr[2*it+1].z, vr[2*it+1].w);
      unsigned t0=__shfl_xor(M1,1), t1=__shfl_xor(M0,1), t2=__shfl_xor(M3,1), t3=__shfl_xor(M2,1);
      bool ob1 = i4 & 1;
      unsigned N0 = ob1 ? t0 : M0;
      unsigned N1 = ob1 ? M1 : t1;
      unsigned N2 = ob1 ? t2 : M2;
      unsigned N3 = ob1 ? M3 : t3;
      unsigned u0s=__shfl_xor(N2,2), u1s=__shfl_xor(N3,2), u2s=__shfl_xor(N0,2), u3s=__shfl_xor(N1,2);
      bool ob2 = i4 & 2;
      unsigned F0 = ob2 ? u0s : N0;
      unsigned F1 = ob2 ? u1s : N1;
      unsigned F2 = ob2 ? N2 : u2s;
      unsigned F3 = ob2 ? N3 : u3s;
      int d = d0 + 2*i4;
      unsigned lo0 = (F0 & 0xffffu) | (F1 << 16);
      unsigned lo1 = (F2 & 0xffffu) | (F3 << 16);
      unsigned hi0 = (F0 >> 16) | (F1 & 0xffff0000u);
      unsigned hi1 = (F2 >> 16) | (F3 & 0xffff0000u);
      int cb = r0*2;
      int sA = ((d >> 1) & 7) << 4;
      *(uint2*)&smem[bb + 16384 + d*128     + (cb ^ sA)] = make_uint2(lo0, lo1);
      *(uint2*)&smem[bb + 16384 + (d+1)*128 + (cb ^ sA)] = make_uint2(hi0, hi1);
    }
  };

  // ---- two phases: qt = 15-j (big), then qt = j (small); every block = 34 tile-steps ----
  #pragma unroll 1
  for (int ph = 0; ph < 2; ++ph){
    const int qt = ph ? j : (15 - j);
    const int nt = 2*qt + 2;
    const int Q0 = qt*128 + rg*32;
    const int qg = Q0 + col;

    // Q fragments
    bf16x8 qf[8];
    #pragma unroll
    for (int dc = 0; dc < 8; ++dc){
      const float* src = Qg + (size_t)qg*DH + dc*16 + hi*8;
      float4 f0 = *(const float4*)(src);
      float4 f1 = *(const float4*)(src + 4);
      uint4 tq;
      tq.x = packbf(f0.x, f0.y); tq.y = packbf(f0.z, f0.w);
      tq.z = packbf(f1.x, f1.y); tq.w = packbf(f1.z, f1.w);
      qf[dc] = __builtin_bit_cast(bf16x8, tq);
    }

    f32x16 o0 = {}, o1 = {}, o2 = {}, o3 = {};
    float m = -1e30f, lsum = 0.f;

    LOADT(0);
    STORET(0);
    __syncthreads();

    #pragma unroll 1
    for (int t = 0; t < nt; ++t){
      const int kvb = t * KVB;
      const int bb  = (t & 1) * 32768;
      const int myk = kvb + par*32;      // this wave's k-half of the tile

      if (t + 1 < nt) LOADT(kvb + KVB);

      if (myk <= Q0 + 31){
        // ---- QK^T (swapped), one 32-wide k half: S^T[k][q] ----
        f32x16 s0 = {};
        const int krow = par*32 + col;
        #pragma unroll
        for (int dc = 0; dc < 8; ++dc){
          uint4 rk = *(const uint4*)&smem[bb + krow*256 + ((dc*32 + hi*16) ^ ((krow & 7) << 4))];
          s0 = mfma32(__builtin_bit_cast(bf16x8, rk), qf[dc], s0);
        }

        s0 = s0 * SC;
        if (myk + 31 > Q0){
          #pragma unroll
          for (int r = 0; r < 16; ++r){
            int kl = (r & 3) + 8*(r >> 2) + 4*hi;
            if (myk + kl > qg) s0[r] = -1e30f;
          }
        }

        float tmax = -1e30f;
        #pragma unroll
        for (int r = 0; r < 16; ++r) tmax = fmaxf(tmax, s0[r]);
        tmax = fmaxf(tmax, __shfl_xor(tmax, 32));
        if (!__all(tmax <= m + 8.0f)){      // T13 defer-max
          float mnew  = fmaxf(m, tmax);
          float alpha = EXP2(m - mnew);
          m = mnew;
          lsum *= alpha;
          o0 *= alpha; o1 *= alpha; o2 *= alpha; o3 *= alpha;
        }

        float ps = 0.f;
        #pragma unroll
        for (int r = 0; r < 16; ++r){ float e = EXP2(s0[r] - m); s0[r] = e; ps += e; }
        lsum += ps;

        unsigned ua0 = packbf(s0[0],  s0[1]),  ua1 = packbf(s0[2],  s0[3]);
        unsigned ua2 = packbf(s0[4],  s0[5]),  ua3 = packbf(s0[6],  s0[7]);
        unsigned ua4 = packbf(s0[8],  s0[9]),  ua5 = packbf(s0[10], s0[11]);
        unsigned ua6 = packbf(s0[12], s0[13]), ua7 = packbf(s0[14], s0[15]);
        bool h = (bool)hi;
        unsigned w0, w1, w2, w3;
        bf16x8 pf[2];
        swap32(ua0, ua2, h, w0, w2); swap32(ua1, ua3, h, w1, w3); pf[0] = mkfrag(w0,w1,w2,w3);
        swap32(ua4, ua6, h, w0, w2); swap32(ua5, ua7, h, w1, w3); pf[1] = mkfrag(w0,w1,w2,w3);

        // ---- PV over this wave's k half ----
        #pragma unroll
        for (int cc = 0; cc < 2; ++cc){
          #pragma unroll
          for (int db = 0; db < 4; ++db){
            int rowd = db*32 + col;
            uint4 rv = *(const uint4*)&smem[bb + 16384 + rowd*128 + ((par*64 + cc*32 + hi*16) ^ (((rowd >> 1) & 7) << 4))];
            f32x16& oo = (db==0)?o0:(db==1)?o1:(db==2)?o2:o3;
            oo = mfma32(__builtin_bit_cast(bf16x8, rv), pf[cc], oo);
          }
        }
      }

      if (t + 1 < nt) STORET((t + 1) & 1);
      __syncthreads();
    }

    // ---- epilogue: combine hi-halves, then parity merge via LDS (2 rounds) ----
    lsum += __shfl_xor(lsum, 32);

    float a0 = 1.f, a1 = 0.f, inv = 0.f;
    #pragma unroll 1
    for (int round = 0; round < 2; ++round){
      const f32x16& pa = round ? o2 : o0;
      const f32x16& pb = round ? o3 : o1;
      if (par == 1){
        #pragma unroll
        for (int i = 0; i < 16; ++i){
          SF[rg*2048 + i*64 + lane]      = pa[i];
          SF[rg*2048 + (16+i)*64 + lane] = pb[i];
        }
        if (round == 0){
          SF[8192 + rg*64 + lane] = m;
          SF[8448 + rg*64 + lane] = lsum;
        }
      }
      __syncthreads();
      if (par == 0){
        if (round == 0){
          float m1 = SF[8192 + rg*64 + lane];
          float l1 = SF[8448 + rg*64 + lane];
          float ms = fmaxf(m, m1);
          a0 = EXP2(m - ms);
          a1 = EXP2(m1 - ms);
          float ls = lsum*a0 + l1*a1;
          inv = 1.0f / ls;
        }
        #pragma unroll
        for (int dbi = 0; dbi < 2; ++dbi){
          const f32x16& oo = round ? (dbi ? o3 : o2) : (dbi ? o1 : o0);
          const int db = round*2 + dbi;
          #pragma unroll
          for (int rg2 = 0; rg2 < 4; ++rg2){
            float4 w;
            w.x = (oo[rg2*4+0]*a0 + SF[rg*2048 + (dbi*16 + rg2*4+0)*64 + lane]*a1) * inv;
            w.y = (oo[rg2*4+1]*a0 + SF[rg*2048 + (dbi*16 + rg2*4+1)*64 + lane]*a1) * inv;
            w.z = (oo[rg2*4+2]*a0 + SF[rg*2048 + (dbi*16 + rg2*4+2)*64 + lane]*a1) * inv;
            w.w = (oo[rg2*4+3]*a0 + SF[rg*2048 + (dbi*16 + rg2*4+3)*64 + lane]*a1) * inv;
            *(float4*)(Og + (size_t)qg*DH + db*32 + rg2*8 + hi*4) = w;
          }
        }
      }
      __syncthreads();
    }
  }
}

extern "C" void kernel_launch(void* const* d_in, const int* in_sizes, int n_in,
                              void* d_out, int out_size, void* d_ws, size_t ws_size,
                              hipStream_t stream) {
  const float* q = (const float*)d_in[0];
  const float* k = (const float*)d_in[1];
  const float* v = (const float*)d_in[2];
  float* out = (float*)d_out;
  dim3 grid(256), block(512);
  attn_fwd<<<grid, block, 0, stream>>>(q, k, v, out);
}

// Round 18
// 96.295 us; speedup vs baseline: 2.0119x; 1.2246x over previous
//
#include <hip/hip_runtime.h>

#define SQ 2048
#define DH 128
#define KVB 64
#define BHN 32
#define ELEMS ((size_t)BHN * SQ * DH)   // 8388608 per tensor

typedef __bf16 bf16x8 __attribute__((ext_vector_type(8)));
typedef float f32x16 __attribute__((ext_vector_type(16)));

__device__ __forceinline__ f32x16 mfma32(bf16x8 a, bf16x8 b, f32x16 c){
  return __builtin_amdgcn_mfma_f32_32x32x16_bf16(a, b, c, 0, 0, 0);
}

#define EXP2 __builtin_amdgcn_exp2f

__device__ __forceinline__ unsigned short f2bf(float f){
  unsigned u = __builtin_bit_cast(unsigned, f);
  u += 0x7fffu + ((u >> 16) & 1u);
  return (unsigned short)(u >> 16);
}
__device__ __forceinline__ unsigned packbf(float a, float b){
  return (unsigned)f2bf(a) | ((unsigned)f2bf(b) << 16);
}

__device__ __forceinline__ void swap32(unsigned a, unsigned b, bool h, unsigned &x, unsigned &y){
  unsigned sb = __shfl_xor(b, 32);
  unsigned sa = __shfl_xor(a, 32);
  x = h ? sb : a;
  y = h ? b : sa;
}

__device__ __forceinline__ bf16x8 mkfrag(unsigned w0, unsigned w1, unsigned w2, unsigned w3){
  uint4 t; t.x = w0; t.y = w1; t.z = w2; t.w = w3;
  return __builtin_bit_cast(bf16x8, t);
}

// ---- one-shot fp32 -> bf16 conversion of K and V into workspace ----
__global__ __launch_bounds__(256, 4)
void convkv(const float* __restrict__ K, const float* __restrict__ V,
            unsigned short* __restrict__ Kb, unsigned short* __restrict__ Vb){
  const size_t g = (size_t)blockIdx.x * 256 + threadIdx.x;   // 262144 threads
  #pragma unroll
  for (int i = 0; i < 4; ++i){
    size_t e = (g + (size_t)i * 262144) * 8;
    float4 a = *(const float4*)(K + e);
    float4 b = *(const float4*)(K + e + 4);
    uint4 o;
    o.x = packbf(a.x, a.y); o.y = packbf(a.z, a.w);
    o.z = packbf(b.x, b.y); o.w = packbf(b.z, b.w);
    *(uint4*)(Kb + e) = o;
    a = *(const float4*)(V + e);
    b = *(const float4*)(V + e + 4);
    o.x = packbf(a.x, a.y); o.y = packbf(a.z, a.w);
    o.z = packbf(b.x, b.y); o.w = packbf(b.z, b.w);
    *(uint4*)(Vb + e) = o;
  }
}

template<bool BF16IN>
__global__ __launch_bounds__(512, 2)
void attn_fwd(const float* __restrict__ Q,
              const float* __restrict__ Kf,
              const float* __restrict__ Vf,
              const unsigned short* __restrict__ Kbg,
              const unsigned short* __restrict__ Vbg,
              float* __restrict__ O)
{
  __shared__ __align__(16) unsigned char smem[65536];
  float* SF = (float*)smem;

  const int tid  = threadIdx.x;
  const int lane = tid & 63;
  const int wid  = tid >> 6;
  const int rg   = wid & 3;
  const int par  = wid >> 2;
  const int col  = lane & 31;
  const int hi   = lane >> 5;
  const int i4   = lane & 3;
  const int d0   = (lane >> 2)*8;

  const int b   = blockIdx.x;
  const int xcd = b & 7;
  const int seq = b >> 3;
  const int bh4 = seq & 3;
  const int j   = seq >> 2;
  const int bh  = xcd + 8*bh4;

  const size_t base = (size_t)bh * SQ * DH;
  const float* Qg = Q + base;
  const float* Kg = Kf + base;
  const float* Vg = Vf + base;
  const unsigned short* Kgb = Kbg + base;
  const unsigned short* Vgb = Vbg + base;
  float* Og = O + base;

  const float SC = 0.08838834764831845f * 1.4426950408889634f;

  float4 kr[4], vr[4];
  uint4  krb[2], vrb[2];

  auto LOADT = [&](int kvb){
    if constexpr (BF16IN){
      #pragma unroll
      for (int i = 0; i < 2; ++i){
        int c = i*512 + tid, r = c >> 4, dc = c & 15;
        krb[i] = *(const uint4*)(Kgb + (size_t)(kvb + r)*DH + dc*8);
      }
      #pragma unroll
      for (int it = 0; it < 2; ++it){
        int row = wid*8 + it*4 + i4;
        vrb[it] = *(const uint4*)(Vgb + (size_t)(kvb + row)*DH + d0);
      }
    } else {
      #pragma unroll
      for (int i = 0; i < 2; ++i){
        int c = i*512 + tid, r = c >> 4, dc = c & 15;
        const float* src = Kg + (size_t)(kvb + r)*DH + dc*8;
        kr[2*i]   = *(const float4*)(src);
        kr[2*i+1] = *(const float4*)(src + 4);
      }
      #pragma unroll
      for (int it = 0; it < 2; ++it){
        int row = wid*8 + it*4 + i4;
        const float* src = Vg + (size_t)(kvb + row)*DH + d0;
        vr[2*it]   = *(const float4*)(src);
        vr[2*it+1] = *(const float4*)(src + 4);
      }
    }
  };

  auto STORET = [&](int bsel){
    const int bb = bsel * 32768;
    #pragma unroll
    for (int i = 0; i < 2; ++i){
      int c = i*512 + tid, r = c >> 4, dc = c & 15;
      uint4 kv;
      if constexpr (BF16IN){
        kv = krb[i];
      } else {
        kv.x = packbf(kr[2*i].x,   kr[2*i].y);
        kv.y = packbf(kr[2*i].z,   kr[2*i].w);
        kv.z = packbf(kr[2*i+1].x, kr[2*i+1].y);
        kv.w = packbf(kr[2*i+1].z, kr[2*i+1].w);
      }
      *(uint4*)&smem[bb + r*256 + ((dc*16) ^ ((r & 7) << 4))] = kv;
    }
    #pragma unroll
    for (int it = 0; it < 2; ++it){
      int r0 = wid*8 + it*4;
      unsigned M0, M1, M2, M3;
      if constexpr (BF16IN){
        M0 = vrb[it].x; M1 = vrb[it].y; M2 = vrb[it].z; M3 = vrb[it].w;
      } else {
        M0 = packbf(vr[2*it].x,   vr[2*it].y);
        M1 = packbf(vr[2*it].z,   vr[2*it].w);
        M2 = packbf(vr[2*it+1].x, vr[2*it+1].y);
        M3 = packbf(vr[2*it+1].z, vr[2*it+1].w);
      }
      unsigned t0=__shfl_xor(M1,1), t1=__shfl_xor(M0,1), t2=__shfl_xor(M3,1), t3=__shfl_xor(M2,1);
      bool ob1 = i4 & 1;
      unsigned N0 = ob1 ? t0 : M0;
      unsigned N1 = ob1 ? M1 : t1;
      unsigned N2 = ob1 ? t2 : M2;
      unsigned N3 = ob1 ? M3 : t3;
      unsigned u0s=__shfl_xor(N2,2), u1s=__shfl_xor(N3,2), u2s=__shfl_xor(N0,2), u3s=__shfl_xor(N1,2);
      bool ob2 = i4 & 2;
      unsigned F0 = ob2 ? u0s : N0;
      unsigned F1 = ob2 ? u1s : N1;
      unsigned F2 = ob2 ? N2 : u2s;
      unsigned F3 = ob2 ? N3 : u3s;
      int d = d0 + 2*i4;
      unsigned lo0 = (F0 & 0xffffu) | (F1 << 16);
      unsigned lo1 = (F2 & 0xffffu) | (F3 << 16);
      unsigned hi0 = (F0 >> 16) | (F1 & 0xffff0000u);
      unsigned hi1 = (F2 >> 16) | (F3 & 0xffff0000u);
      int cb = r0*2;
      int sA = ((d >> 1) & 7) << 4;
      *(uint2*)&smem[bb + 16384 + d*128     + (cb ^ sA)] = make_uint2(lo0, lo1);
      *(uint2*)&smem[bb + 16384 + (d+1)*128 + (cb ^ sA)] = make_uint2(hi0, hi1);
    }
  };

  #pragma unroll 1
  for (int ph = 0; ph < 2; ++ph){
    const int qt = ph ? j : (15 - j);
    const int nt = 2*qt + 2;
    const int Q0 = qt*128 + rg*32;
    const int qg = Q0 + col;

    bf16x8 qf[8];
    #pragma unroll
    for (int dc = 0; dc < 8; ++dc){
      const float* src = Qg + (size_t)qg*DH + dc*16 + hi*8;
      float4 f0 = *(const float4*)(src);
      float4 f1 = *(const float4*)(src + 4);
      uint4 tq;
      tq.x = packbf(f0.x, f0.y); tq.y = packbf(f0.z, f0.w);
      tq.z = packbf(f1.x, f1.y); tq.w = packbf(f1.z, f1.w);
      qf[dc] = __builtin_bit_cast(bf16x8, tq);
    }

    f32x16 o0 = {}, o1 = {}, o2 = {}, o3 = {};
    float m = -1e30f, lsum = 0.f;

    LOADT(0);
    STORET(0);
    __syncthreads();

    #pragma unroll 1
    for (int t = 0; t < nt; ++t){
      const int kvb = t * KVB;
      const int bb  = (t & 1) * 32768;
      const int myk = kvb + par*32;

      if (t + 1 < nt) LOADT(kvb + KVB);

      if (myk <= Q0 + 31){
        f32x16 s0 = {};
        const int krow = par*32 + col;
        #pragma unroll
        for (int dc = 0; dc < 8; ++dc){
          uint4 rk = *(const uint4*)&smem[bb + krow*256 + ((dc*32 + hi*16) ^ ((krow & 7) << 4))];
          s0 = mfma32(__builtin_bit_cast(bf16x8, rk), qf[dc], s0);
        }

        s0 = s0 * SC;
        if (myk + 31 > Q0){
          #pragma unroll
          for (int r = 0; r < 16; ++r){
            int kl = (r & 3) + 8*(r >> 2) + 4*hi;
            if (myk + kl > qg) s0[r] = -1e30f;
          }
        }

        float tmax = -1e30f;
        #pragma unroll
        for (int r = 0; r < 16; ++r) tmax = fmaxf(tmax, s0[r]);
        tmax = fmaxf(tmax, __shfl_xor(tmax, 32));
        if (!__all(tmax <= m + 8.0f)){
          float mnew  = fmaxf(m, tmax);
          float alpha = EXP2(m - mnew);
          m = mnew;
          lsum *= alpha;
          o0 *= alpha; o1 *= alpha; o2 *= alpha; o3 *= alpha;
        }

        float ps = 0.f;
        #pragma unroll
        for (int r = 0; r < 16; ++r){ float e = EXP2(s0[r] - m); s0[r] = e; ps += e; }
        lsum += ps;

        unsigned ua0 = packbf(s0[0],  s0[1]),  ua1 = packbf(s0[2],  s0[3]);
        unsigned ua2 = packbf(s0[4],  s0[5]),  ua3 = packbf(s0[6],  s0[7]);
        unsigned ua4 = packbf(s0[8],  s0[9]),  ua5 = packbf(s0[10], s0[11]);
        unsigned ua6 = packbf(s0[12], s0[13]), ua7 = packbf(s0[14], s0[15]);
        bool h = (bool)hi;
        unsigned w0, w1, w2, w3;
        bf16x8 pf[2];
        swap32(ua0, ua2, h, w0, w2); swap32(ua1, ua3, h, w1, w3); pf[0] = mkfrag(w0,w1,w2,w3);
        swap32(ua4, ua6, h, w0, w2); swap32(ua5, ua7, h, w1, w3); pf[1] = mkfrag(w0,w1,w2,w3);

        #pragma unroll
        for (int cc = 0; cc < 2; ++cc){
          #pragma unroll
          for (int db = 0; db < 4; ++db){
            int rowd = db*32 + col;
            uint4 rv = *(const uint4*)&smem[bb + 16384 + rowd*128 + ((par*64 + cc*32 + hi*16) ^ (((rowd >> 1) & 7) << 4))];
            f32x16& oo = (db==0)?o0:(db==1)?o1:(db==2)?o2:o3;
            oo = mfma32(__builtin_bit_cast(bf16x8, rv), pf[cc], oo);
          }
        }
      }

      if (t + 1 < nt) STORET((t + 1) & 1);
      __syncthreads();
    }

    // ---- epilogue: combine hi-halves, then parity merge via LDS ----
    lsum += __shfl_xor(lsum, 32);

    float a0 = 1.f, a1 = 0.f, inv = 0.f;
    #pragma unroll 1
    for (int round = 0; round < 2; ++round){
      const f32x16& pa = round ? o2 : o0;
      const f32x16& pb = round ? o3 : o1;
      if (par == 1){
        #pragma unroll
        for (int i = 0; i < 16; ++i){
          SF[rg*2048 + i*64 + lane]      = pa[i];
          SF[rg*2048 + (16+i)*64 + lane] = pb[i];
        }
        if (round == 0){
          SF[8192 + rg*64 + lane] = m;
          SF[8448 + rg*64 + lane] = lsum;
        }
      }
      __syncthreads();
      if (par == 0){
        if (round == 0){
          float m1 = SF[8192 + rg*64 + lane];
          float l1 = SF[8448 + rg*64 + lane];
          float ms = fmaxf(m, m1);
          a0 = EXP2(m - ms);
          a1 = EXP2(m1 - ms);
          float ls = lsum*a0 + l1*a1;
          inv = 1.0f / ls;
        }
        #pragma unroll
        for (int dbi = 0; dbi < 2; ++dbi){
          const f32x16& oo = round ? (dbi ? o3 : o2) : (dbi ? o1 : o0);
          const int db = round*2 + dbi;
          #pragma unroll
          for (int rg2 = 0; rg2 < 4; ++rg2){
            float4 w;
            w.x = (oo[rg2*4+0]*a0 + SF[rg*2048 + (dbi*16 + rg2*4+0)*64 + lane]*a1) * inv;
            w.y = (oo[rg2*4+1]*a0 + SF[rg*2048 + (dbi*16 + rg2*4+1)*64 + lane]*a1) * inv;
            w.z = (oo[rg2*4+2]*a0 + SF[rg*2048 + (dbi*16 + rg2*4+2)*64 + lane]*a1) * inv;
            w.w = (oo[rg2*4+3]*a0 + SF[rg*2048 + (dbi*16 + rg2*4+3)*64 + lane]*a1) * inv;
            *(float4*)(Og + (size_t)qg*DH + db*32 + rg2*8 + hi*4) = w;
          }
        }
      }
      __syncthreads();
    }
  }
}

extern "C" void kernel_launch(void* const* d_in, const int* in_sizes, int n_in,
                              void* d_out, int out_size, void* d_ws, size_t ws_size,
                              hipStream_t stream) {
  const float* q = (const float*)d_in[0];
  const float* k = (const float*)d_in[1];
  const float* v = (const float*)d_in[2];
  float* out = (float*)d_out;

  const size_t need = 2 * ELEMS * sizeof(unsigned short);   // 32 MB
  if (ws_size >= need){
    unsigned short* kb = (unsigned short*)d_ws;
    unsigned short* vb = kb + ELEMS;
    convkv<<<1024, 256, 0, stream>>>(k, v, kb, vb);
    attn_fwd<true><<<256, 512, 0, stream>>>(q, k, v, kb, vb, out);
  } else {
    attn_fwd<false><<<256, 512, 0, stream>>>(q, k, v, nullptr, nullptr, out);
  }
}